// Round 1
// baseline (197.789 us; speedup 1.0000x reference)
//
#include <hip/hip_runtime.h>
#include <stdint.h>

typedef unsigned short u16;
typedef unsigned int u32;
typedef __bf16 bf16x8 __attribute__((ext_vector_type(8)));
typedef float f32x4 __attribute__((ext_vector_type(4)));

// fp32 -> bf16 round-to-nearest-even
__device__ __forceinline__ u16 f2bf(float f) {
  u32 u = __float_as_uint(f);
  u = (u + 0x7fffu + ((u >> 16) & 1u)) >> 16;
  return (u16)u;
}

// async global->LDS, 16B per lane; lds base must be wave-uniform (HW adds lane*16)
__device__ __forceinline__ void gload16(const void* g, void* l) {
  __builtin_amdgcn_global_load_lds(
      (const __attribute__((address_space(1))) void*)g,
      (__attribute__((address_space(3))) void*)l, 16, 0, 0);
}

// ---------------- fp32 -> bf16 convert (query/key/value) ----------------
__global__ __launch_bounds__(256) void cvt_qkv(
    const float* __restrict__ q, const float* __restrict__ k,
    const float* __restrict__ v, u16* __restrict__ dst) {
  const float* s = (blockIdx.y == 0) ? q : (blockIdx.y == 1) ? k : v;
  u16* d = dst + (size_t)blockIdx.y * 4194304u;
  int e = (blockIdx.x * 256 + threadIdx.x) * 8;
  float4 a = *(const float4*)(s + e);
  float4 b = *(const float4*)(s + e + 4);
  uint4 o;
  o.x = (u32)f2bf(a.x) | ((u32)f2bf(a.y) << 16);
  o.y = (u32)f2bf(a.z) | ((u32)f2bf(a.w) << 16);
  o.z = (u32)f2bf(b.x) | ((u32)f2bf(b.y) << 16);
  o.w = (u32)f2bf(b.z) | ((u32)f2bf(b.w) << 16);
  *(uint4*)(d + e) = o;
}

// ---------------- W [1024][1024] fp32 -> W^T bf16 ----------------
__global__ __launch_bounds__(512) void trans_w(
    const float* __restrict__ w0, const float* __restrict__ w1,
    const float* __restrict__ w2, const float* __restrict__ w3,
    u16* __restrict__ wt) {
  const float* W = (blockIdx.z == 0) ? w0 : (blockIdx.z == 1) ? w1
                   : (blockIdx.z == 2) ? w2 : w3;
  u16* Wt = wt + (size_t)blockIdx.z * 1048576u;
  __shared__ float tile[64][65];
  int x0 = blockIdx.x * 64, y0 = blockIdx.y * 64;
  int tx = threadIdx.x, ty = threadIdx.y;
#pragma unroll
  for (int j = 0; j < 8; ++j)
    tile[ty + j * 8][tx] = W[(size_t)(y0 + ty + j * 8) * 1024 + x0 + tx];
  __syncthreads();
#pragma unroll
  for (int j = 0; j < 8; ++j)
    Wt[(size_t)(x0 + ty + j * 8) * 1024 + y0 + tx] = f2bf(tile[tx][ty + j * 8]);
}

// ---------------- GEMM: C[i][j] = sum_k A[i][k]*Bt[j][k] (+bias) ----------------
// A: MxK bf16 row-major, Bt: NxK bf16 row-major. 128x128 tile, BK=64,
// 4 waves (2x2), each wave 64x64 via 4x4 frags of 16x16x32 MFMA.
// LDS XOR-swizzle (rule #21): linear dest + inverse-swizzled global source,
// swizzled ds_read.
template <bool BF16OUT, bool ROWBIAS>
__global__ __launch_bounds__(256, 2) void gemm_bt(
    const u16* __restrict__ A, const u16* __restrict__ Bt,
    const float* __restrict__ bias0, const float* __restrict__ bias1,
    void* __restrict__ Cv, int M, int N, int K, int sA, int sB, int sC) {
  const int z = blockIdx.z;
  A += (size_t)z * sA;
  Bt += (size_t)z * sB;
  const float* bias = (z == 0) ? bias0 : bias1;

  __shared__ __align__(16) u16 ldsA[128 * 64];
  __shared__ __align__(16) u16 ldsB[128 * 64];

  const int tid = threadIdx.x;
  const int lane = tid & 63, wv = tid >> 6;
  const int wr = wv >> 1, wc = wv & 1;
  const int l15 = lane & 15, l4 = lane >> 4;
  const int bm = blockIdx.x * 128, bn = blockIdx.y * 128;

  const f32x4 zero4 = {0.f, 0.f, 0.f, 0.f};
  f32x4 acc[4][4];
#pragma unroll
  for (int i = 0; i < 4; ++i)
#pragma unroll
    for (int j = 0; j < 4; ++j) acc[i][j] = zero4;

  const int nK = K >> 6;
  for (int kt = 0; kt < nK; ++kt) {
    __syncthreads();
#pragma unroll
    for (int g = 0; g < 4; ++g) {
      int p = g * 256 + tid;            // chunk id (per-lane)
      int row = p >> 3;
      int ss = (p & 7) ^ (row & 7);     // inverse-swizzled source slot
      gload16(A + (size_t)(bm + row) * K + kt * 64 + ss * 8,
              (char*)ldsA + (g * 256 + wv * 64) * 16);
    }
#pragma unroll
    for (int g = 0; g < 4; ++g) {
      int p = g * 256 + tid;
      int row = p >> 3;
      int ss = (p & 7) ^ (row & 7);
      gload16(Bt + (size_t)(bn + row) * K + kt * 64 + ss * 8,
              (char*)ldsB + (g * 256 + wv * 64) * 16);
    }
    __syncthreads();

    bf16x8 af[4][2], bfr[4][2];
#pragma unroll
    for (int mf = 0; mf < 4; ++mf) {
      int row = wr * 64 + mf * 16 + l15;
#pragma unroll
      for (int ks = 0; ks < 2; ++ks) {
        int byt = row * 128 + ((ks * 64 + l4 * 16) ^ ((row & 7) << 4));
        af[mf][ks] = *(const bf16x8*)((const char*)ldsA + byt);
      }
    }
#pragma unroll
    for (int nf = 0; nf < 4; ++nf) {
      int row = wc * 64 + nf * 16 + l15;
#pragma unroll
      for (int ks = 0; ks < 2; ++ks) {
        int byt = row * 128 + ((ks * 64 + l4 * 16) ^ ((row & 7) << 4));
        bfr[nf][ks] = *(const bf16x8*)((const char*)ldsB + byt);
      }
    }
#pragma unroll
    for (int mf = 0; mf < 4; ++mf)
#pragma unroll
      for (int nf = 0; nf < 4; ++nf) {
        acc[mf][nf] = __builtin_amdgcn_mfma_f32_16x16x32_bf16(
            af[mf][0], bfr[nf][0], acc[mf][nf], 0, 0, 0);
        acc[mf][nf] = __builtin_amdgcn_mfma_f32_16x16x32_bf16(
            af[mf][1], bfr[nf][1], acc[mf][nf], 0, 0, 0);
      }
  }

  // epilogue
  float bcol[4];
  if (!ROWBIAS) {
#pragma unroll
    for (int nf = 0; nf < 4; ++nf)
      bcol[nf] = bias[bn + wc * 64 + nf * 16 + l15];
  }
#pragma unroll
  for (int mf = 0; mf < 4; ++mf) {
#pragma unroll
    for (int i = 0; i < 4; ++i) {
      int r = bm + wr * 64 + mf * 16 + l4 * 4 + i;
      float br = ROWBIAS ? bias[r] : 0.f;
#pragma unroll
      for (int nf = 0; nf < 4; ++nf) {
        int c = bn + wc * 64 + nf * 16 + l15;
        float val = acc[mf][nf][i] + (ROWBIAS ? br : bcol[nf]);
        size_t off = (size_t)r * N + c;
        if (BF16OUT)
          ((u16*)Cv + (size_t)z * sC)[off] = f2bf(val);
        else
          ((float*)Cv)[off] = val;
      }
    }
  }
}

// ---------------- causal flash attention ----------------
// Q,K: [B*S][1024] bf16 (head h at cols h*64..h*64+63). Vt: [h*64+d][B*S] bf16.
// Grid: (qtile 0..31, b*16+h). 4 waves, each owns 16 q-rows; KVBLK=64.
// scale = 1/sqrt(2048) (reference divides by sqrt(Sk), NOT sqrt(hd)).
__global__ __launch_bounds__(256, 4) void attn_k(
    const u16* __restrict__ Q, const u16* __restrict__ Kb,
    const u16* __restrict__ Vt, u16* __restrict__ ctx) {
  const int qt = blockIdx.x;
  const int bh = blockIdx.y;
  const int b = bh >> 4, h = bh & 15;
  const int tid = threadIdx.x;
  const int lane = tid & 63, wv = tid >> 6;
  const int l15 = lane & 15, l4 = lane >> 4;

  __shared__ __align__(16) u16 Kt[64 * 64];      // [kv][d], swizzled
  __shared__ __align__(16) u16 Vl[64 * 64];      // [d][kv], swizzled
  __shared__ __align__(16) u16 Pl[4][16 * 64];   // per-wave P, swizzled

  const float SC2 = 0.0318793585f;  // (1/sqrt(2048)) * log2(e)

  const u16* qptr =
      Q + (size_t)(b * 2048 + qt * 64 + wv * 16 + l15) * 1024 + h * 64;
  bf16x8 qf0 = *(const bf16x8*)(qptr + l4 * 8);
  bf16x8 qf1 = *(const bf16x8*)(qptr + 32 + l4 * 8);

  const f32x4 zero4 = {0.f, 0.f, 0.f, 0.f};
  float m2[4], lsum[4];
  f32x4 oacc[4];
#pragma unroll
  for (int i = 0; i < 4; ++i) {
    m2[i] = -1e30f;
    lsum[i] = 0.f;
    oacc[i] = zero4;
  }

  const u16* KB = Kb + (size_t)(b * 2048) * 1024 + h * 64;
  const u16* VB = Vt + (size_t)(h * 64) * 4096 + b * 2048;

  for (int j = 0; j <= qt; ++j) {
    __syncthreads();
#pragma unroll
    for (int g = 0; g < 2; ++g) {
      int p = g * 256 + tid;
      int row = p >> 3;
      int ss = (p & 7) ^ (row & 7);
      gload16(KB + (size_t)(j * 64 + row) * 1024 + ss * 8,
              (char*)Kt + (g * 256 + wv * 64) * 16);
    }
#pragma unroll
    for (int g = 0; g < 2; ++g) {
      int p = g * 256 + tid;
      int d = p >> 3;
      int ss = (p & 7) ^ (d & 7);
      gload16(VB + (size_t)d * 4096 + j * 64 + ss * 8,
              (char*)Vl + (g * 256 + wv * 64) * 16);
    }
    __syncthreads();

    // S = Q K^T
    f32x4 sf[4];
#pragma unroll
    for (int nt = 0; nt < 4; ++nt) {
      int row = nt * 16 + l15;
      int c0 = (l4 * 16) ^ ((row & 7) << 4);
      int c1 = (64 + l4 * 16) ^ ((row & 7) << 4);
      bf16x8 k0 = *(const bf16x8*)((const char*)Kt + row * 128 + c0);
      bf16x8 k1 = *(const bf16x8*)((const char*)Kt + row * 128 + c1);
      f32x4 s = zero4;
      s = __builtin_amdgcn_mfma_f32_16x16x32_bf16(qf0, k0, s, 0, 0, 0);
      s = __builtin_amdgcn_mfma_f32_16x16x32_bf16(qf1, k1, s, 0, 0, 0);
      sf[nt] = s;
    }

    // scale + causal mask (log2 domain)
    const bool diag = (j == qt);
    float p4[4][4];
#pragma unroll
    for (int nt = 0; nt < 4; ++nt)
#pragma unroll
      for (int i = 0; i < 4; ++i) {
        float s = sf[nt][i] * SC2;
        if (diag && (nt * 16 + l15 > wv * 16 + l4 * 4 + i)) s = -1e30f;
        p4[nt][i] = s;
      }

    // online softmax
    float rm[4];
#pragma unroll
    for (int i = 0; i < 4; ++i)
      rm[i] = fmaxf(fmaxf(p4[0][i], p4[1][i]), fmaxf(p4[2][i], p4[3][i]));
#pragma unroll
    for (int d = 1; d < 16; d <<= 1)
#pragma unroll
      for (int i = 0; i < 4; ++i)
        rm[i] = fmaxf(rm[i], __shfl_xor(rm[i], d, 64));
    float cexp[4], rs[4];
#pragma unroll
    for (int i = 0; i < 4; ++i) {
      float mn = fmaxf(m2[i], rm[i]);
      cexp[i] = exp2f(m2[i] - mn);
      m2[i] = mn;
    }
#pragma unroll
    for (int nt = 0; nt < 4; ++nt)
#pragma unroll
      for (int i = 0; i < 4; ++i) p4[nt][i] = exp2f(p4[nt][i] - m2[i]);
#pragma unroll
    for (int i = 0; i < 4; ++i)
      rs[i] = (p4[0][i] + p4[1][i]) + (p4[2][i] + p4[3][i]);
#pragma unroll
    for (int d = 1; d < 16; d <<= 1)
#pragma unroll
      for (int i = 0; i < 4; ++i) rs[i] += __shfl_xor(rs[i], d, 64);
#pragma unroll
    for (int i = 0; i < 4; ++i) lsum[i] = lsum[i] * cexp[i] + rs[i];
#pragma unroll
    for (int nt = 0; nt < 4; ++nt)
#pragma unroll
      for (int i = 0; i < 4; ++i) oacc[nt][i] *= cexp[i];

    // P -> LDS (bf16, A-layout friendly, swizzled)
#pragma unroll
    for (int nt = 0; nt < 4; ++nt)
#pragma unroll
      for (int i = 0; i < 4; ++i) {
        int r = l4 * 4 + i;
        int byt = r * 128 + ((nt * 32 + l15 * 2) ^ ((r & 7) << 4));
        *(u16*)((char*)Pl[wv] + byt) = f2bf(p4[nt][i]);
      }
    __syncthreads();

    // O += P V
    bf16x8 pa0, pa1;
    {
      int r = l15;
      int c0 = (l4 * 16) ^ ((r & 7) << 4);
      int c1 = (64 + l4 * 16) ^ ((r & 7) << 4);
      pa0 = *(const bf16x8*)((const char*)Pl[wv] + r * 128 + c0);
      pa1 = *(const bf16x8*)((const char*)Pl[wv] + r * 128 + c1);
    }
#pragma unroll
    for (int nt = 0; nt < 4; ++nt) {
      int d = nt * 16 + l15;
      int c0 = (l4 * 16) ^ ((d & 7) << 4);
      int c1 = (64 + l4 * 16) ^ ((d & 7) << 4);
      bf16x8 v0 = *(const bf16x8*)((const char*)Vl + d * 128 + c0);
      bf16x8 v1 = *(const bf16x8*)((const char*)Vl + d * 128 + c1);
      oacc[nt] = __builtin_amdgcn_mfma_f32_16x16x32_bf16(pa0, v0, oacc[nt], 0, 0, 0);
      oacc[nt] = __builtin_amdgcn_mfma_f32_16x16x32_bf16(pa1, v1, oacc[nt], 0, 0, 0);
    }
  }

  // normalize + store ctx (bf16, [b*2048+q][h*64+d])
  u16* cb = ctx + (size_t)(b * 2048 + qt * 64 + wv * 16) * 1024 + h * 64;
#pragma unroll
  for (int i = 0; i < 4; ++i) {
    float inv = 1.f / lsum[i];
    int r = l4 * 4 + i;
#pragma unroll
    for (int nt = 0; nt < 4; ++nt)
      cb[(size_t)r * 1024 + nt * 16 + l15] = f2bf(oacc[nt][i] * inv);
  }
}

// ---------------- launch ----------------
extern "C" void kernel_launch(void* const* d_in, const int* in_sizes, int n_in,
                              void* d_out, int out_size, void* d_ws,
                              size_t ws_size, hipStream_t stream) {
  const float* q  = (const float*)d_in[0];
  const float* k  = (const float*)d_in[1];
  const float* v  = (const float*)d_in[2];
  const float* Wq = (const float*)d_in[3];
  const float* bq = (const float*)d_in[4];
  const float* Wk = (const float*)d_in[5];
  const float* bk = (const float*)d_in[6];
  const float* Wv = (const float*)d_in[7];
  const float* bv = (const float*)d_in[8];
  const float* Wo = (const float*)d_in[9];
  const float* bo = (const float*)d_in[10];

  // workspace layout (40 MiB):
  //   [0,24M):   Xb = bf16(query|key|value), 3 x 4194304 elems
  //              (first 8 MiB reused later as ctx — Xb fully consumed first)
  //   [24M,32M): Wt = bf16 W^T for q,k,v,o, 4 x 1048576 elems
  //   [32M,40M): VtG = V^T bf16 [1024][4096]
  // d_out (16 MiB) doubles as scratch for Qb|Kb bf16 before the final GEMM
  // fully overwrites it (deterministic each call).
  char* ws = (char*)d_ws;
  u16* Xb  = (u16*)ws;
  u16* Wt  = (u16*)(ws + 25165824);
  u16* VtG = (u16*)(ws + 33554432);
  u16* ctx = Xb;
  u16* Qb  = (u16*)d_out;
  u16* Kb  = Qb + 4194304;

  cvt_qkv<<<dim3(2048, 3), 256, 0, stream>>>(q, k, v, Xb);
  trans_w<<<dim3(16, 16, 4), dim3(64, 8), 0, stream>>>(Wq, Wk, Wv, Wo, Wt);
  // Q,K projections (z-batched): C = X @ W + b -> bf16
  gemm_bt<true, false><<<dim3(32, 8, 2), 256, 0, stream>>>(
      Xb, Wt, bq, bk, (void*)Qb, 4096, 1024, 1024, 4194304, 1048576, 4194304);
  // V^T = Wv^T . X^T (+bv per row) -> VtG[1024][4096]
  gemm_bt<true, true><<<dim3(8, 32, 1), 256, 0, stream>>>(
      Wt + 2 * 1048576, Xb + 2 * 4194304, bv, bv, (void*)VtG,
      1024, 4096, 1024, 0, 0, 0);
  attn_k<<<dim3(32, 32), 256, 0, stream>>>(Qb, Kb, VtG, ctx);
  // out = ctx @ Wo + bo -> fp32 d_out
  gemm_bt<false, false><<<dim3(32, 8, 1), 256, 0, stream>>>(
      ctx, Wt + 3 * 1048576, bo, bo, d_out, 4096, 1024, 1024, 0, 0, 0);
}

// Round 2
// 155.949 us; speedup vs baseline: 1.2683x; 1.2683x over previous
//
#include <hip/hip_runtime.h>
#include <stdint.h>

typedef unsigned short u16;
typedef unsigned int u32;
typedef __bf16 bf16x8 __attribute__((ext_vector_type(8)));
typedef float f32x4 __attribute__((ext_vector_type(4)));

// fp32 -> bf16 round-to-nearest-even
__device__ __forceinline__ u16 f2bf(float f) {
  u32 u = __float_as_uint(f);
  u = (u + 0x7fffu + ((u >> 16) & 1u)) >> 16;
  return (u16)u;
}

// async global->LDS, 16B per lane; lds base must be wave-uniform (HW adds lane*16)
__device__ __forceinline__ void gload16(const void* g, void* l) {
  __builtin_amdgcn_global_load_lds(
      (const __attribute__((address_space(1))) void*)g,
      (__attribute__((address_space(3))) void*)l, 16, 0, 0);
}

// ---------------- fp32 -> bf16 convert (query/key/value) ----------------
__global__ __launch_bounds__(256) void cvt_qkv(
    const float* __restrict__ q, const float* __restrict__ k,
    const float* __restrict__ v, u16* __restrict__ dst) {
  const float* s = (blockIdx.y == 0) ? q : (blockIdx.y == 1) ? k : v;
  u16* d = dst + (size_t)blockIdx.y * 4194304u;
  int e = (blockIdx.x * 256 + threadIdx.x) * 8;
  float4 a = *(const float4*)(s + e);
  float4 b = *(const float4*)(s + e + 4);
  uint4 o;
  o.x = (u32)f2bf(a.x) | ((u32)f2bf(a.y) << 16);
  o.y = (u32)f2bf(a.z) | ((u32)f2bf(a.w) << 16);
  o.z = (u32)f2bf(b.x) | ((u32)f2bf(b.y) << 16);
  o.w = (u32)f2bf(b.z) | ((u32)f2bf(b.w) << 16);
  *(uint4*)(d + e) = o;
}

// ---------------- W [1024][1024] fp32 -> W^T bf16 ----------------
__global__ __launch_bounds__(512) void trans_w(
    const float* __restrict__ w0, const float* __restrict__ w1,
    const float* __restrict__ w2, const float* __restrict__ w3,
    u16* __restrict__ wt) {
  const float* W = (blockIdx.z == 0) ? w0 : (blockIdx.z == 1) ? w1
                   : (blockIdx.z == 2) ? w2 : w3;
  u16* Wt = wt + (size_t)blockIdx.z * 1048576u;
  __shared__ float tile[64][65];
  int x0 = blockIdx.x * 64, y0 = blockIdx.y * 64;
  int tx = threadIdx.x, ty = threadIdx.y;
#pragma unroll
  for (int j = 0; j < 8; ++j)
    tile[ty + j * 8][tx] = W[(size_t)(y0 + ty + j * 8) * 1024 + x0 + tx];
  __syncthreads();
#pragma unroll
  for (int j = 0; j < 8; ++j)
    Wt[(size_t)(x0 + ty + j * 8) * 1024 + y0 + tx] = f2bf(tile[tx][ty + j * 8]);
}

// ---------------- GEMM: C[i][j] = (sum_k A[i][k]*Bt[j][k] + bias) * osc ----
// A: MxK bf16 row-major, Bt: NxK bf16 row-major. 128x128 tile, BK=64,
// 4 waves (2x2), each wave 64x64 via 4x4 frags of 16x16x32 MFMA.
// LDS XOR-swizzle (rule #21): linear dest + inverse-swizzled global source,
// swizzled ds_read.
template <bool BF16OUT, bool ROWBIAS>
__global__ __launch_bounds__(256, 2) void gemm_bt(
    const u16* __restrict__ A, const u16* __restrict__ Bt,
    const float* __restrict__ bias0, const float* __restrict__ bias1,
    float osc0, float osc1,
    void* __restrict__ Cv, int M, int N, int K, int sA, int sB, int sC) {
  const int z = blockIdx.z;
  A += (size_t)z * sA;
  Bt += (size_t)z * sB;
  const float* bias = (z == 0) ? bias0 : bias1;
  const float osc = (z == 0) ? osc0 : osc1;

  __shared__ __align__(16) u16 ldsA[128 * 64];
  __shared__ __align__(16) u16 ldsB[128 * 64];

  const int tid = threadIdx.x;
  const int lane = tid & 63, wv = tid >> 6;
  const int wr = wv >> 1, wc = wv & 1;
  const int l15 = lane & 15, l4 = lane >> 4;
  const int bm = blockIdx.x * 128, bn = blockIdx.y * 128;

  const f32x4 zero4 = {0.f, 0.f, 0.f, 0.f};
  f32x4 acc[4][4];
#pragma unroll
  for (int i = 0; i < 4; ++i)
#pragma unroll
    for (int j = 0; j < 4; ++j) acc[i][j] = zero4;

  const int nK = K >> 6;
  for (int kt = 0; kt < nK; ++kt) {
    __syncthreads();
#pragma unroll
    for (int g = 0; g < 4; ++g) {
      int p = g * 256 + tid;            // chunk id (per-lane)
      int row = p >> 3;
      int ss = (p & 7) ^ (row & 7);     // inverse-swizzled source slot
      gload16(A + (size_t)(bm + row) * K + kt * 64 + ss * 8,
              (char*)ldsA + (g * 256 + wv * 64) * 16);
    }
#pragma unroll
    for (int g = 0; g < 4; ++g) {
      int p = g * 256 + tid;
      int row = p >> 3;
      int ss = (p & 7) ^ (row & 7);
      gload16(Bt + (size_t)(bn + row) * K + kt * 64 + ss * 8,
              (char*)ldsB + (g * 256 + wv * 64) * 16);
    }
    __syncthreads();

    bf16x8 af[4][2], bfr[4][2];
#pragma unroll
    for (int mf = 0; mf < 4; ++mf) {
      int row = wr * 64 + mf * 16 + l15;
#pragma unroll
      for (int ks = 0; ks < 2; ++ks) {
        int byt = row * 128 + ((ks * 64 + l4 * 16) ^ ((row & 7) << 4));
        af[mf][ks] = *(const bf16x8*)((const char*)ldsA + byt);
      }
    }
#pragma unroll
    for (int nf = 0; nf < 4; ++nf) {
      int row = wc * 64 + nf * 16 + l15;
#pragma unroll
      for (int ks = 0; ks < 2; ++ks) {
        int byt = row * 128 + ((ks * 64 + l4 * 16) ^ ((row & 7) << 4));
        bfr[nf][ks] = *(const bf16x8*)((const char*)ldsB + byt);
      }
    }
#pragma unroll
    for (int mf = 0; mf < 4; ++mf)
#pragma unroll
      for (int nf = 0; nf < 4; ++nf) {
        acc[mf][nf] = __builtin_amdgcn_mfma_f32_16x16x32_bf16(
            af[mf][0], bfr[nf][0], acc[mf][nf], 0, 0, 0);
        acc[mf][nf] = __builtin_amdgcn_mfma_f32_16x16x32_bf16(
            af[mf][1], bfr[nf][1], acc[mf][nf], 0, 0, 0);
      }
  }

  // epilogue
  float bcol[4];
  if (!ROWBIAS) {
#pragma unroll
    for (int nf = 0; nf < 4; ++nf)
      bcol[nf] = bias[bn + wc * 64 + nf * 16 + l15];
  }
#pragma unroll
  for (int mf = 0; mf < 4; ++mf) {
#pragma unroll
    for (int i = 0; i < 4; ++i) {
      int r = bm + wr * 64 + mf * 16 + l4 * 4 + i;
      float br = ROWBIAS ? bias[r] : 0.f;
#pragma unroll
      for (int nf = 0; nf < 4; ++nf) {
        int c = bn + wc * 64 + nf * 16 + l15;
        float val = (acc[mf][nf][i] + (ROWBIAS ? br : bcol[nf])) * osc;
        size_t off = (size_t)r * N + c;
        if (BF16OUT)
          ((u16*)Cv + (size_t)z * sC)[off] = f2bf(val);
        else
          ((float*)Cv)[off] = val;
      }
    }
  }
}

// ---------------- causal flash attention ----------------
// Q,K: [B*S][1024] bf16 (head h at cols h*64..h*64+63). Q is pre-scaled by
// log2(e)/sqrt(2048) in its projection epilogue. Vt: [h*64+d][B*S] bf16.
// Grid: (pair 0..15, b*16+h). Block handles q-tiles x and 31-x in ONE kv
// loop sharing K/V tiles (tile j feeds both while j <= x). 4 waves x 16
// q-rows per q-tile; KVBLK=64; single-barrier double-buffered K/V staging.
__global__ __launch_bounds__(256, 2) void attn_k(
    const u16* __restrict__ Q, const u16* __restrict__ Kb,
    const u16* __restrict__ Vt, u16* __restrict__ ctx) {
  const int qtA = blockIdx.x;        // 0..15 (short)
  const int qtB = 31 - blockIdx.x;   // 16..31 (long)
  const int nta = qtA + 1, ntb = qtB + 1;
  const int bh = blockIdx.y;
  const int b = bh >> 4, h = bh & 15;
  const int tid = threadIdx.x;
  const int lane = tid & 63, wv = tid >> 6;
  const int l15 = lane & 15, l4 = lane >> 4;

  __shared__ __align__(16) u16 Kt[2][64 * 64];   // [kv][d], swizzled
  __shared__ __align__(16) u16 Vl[2][64 * 64];   // [d][kv], swizzled
  __shared__ __align__(16) u16 Pl[4][16 * 64];   // per-wave P, swizzled

  const u16* KB = Kb + (size_t)(b * 2048) * 1024 + h * 64;
  const u16* VB = Vt + (size_t)(h * 64) * 4096 + b * 2048;

  // Q fragments for both q-tiles (pre-scaled by log2e/sqrt(2048))
  const u16* qpa =
      Q + (size_t)(b * 2048 + qtA * 64 + wv * 16 + l15) * 1024 + h * 64;
  const u16* qpb =
      Q + (size_t)(b * 2048 + qtB * 64 + wv * 16 + l15) * 1024 + h * 64;
  bf16x8 qa0 = *(const bf16x8*)(qpa + l4 * 8);
  bf16x8 qa1 = *(const bf16x8*)(qpa + 32 + l4 * 8);
  bf16x8 qb0 = *(const bf16x8*)(qpb + l4 * 8);
  bf16x8 qb1 = *(const bf16x8*)(qpb + 32 + l4 * 8);

  const f32x4 zero4 = {0.f, 0.f, 0.f, 0.f};
  float mA[4], lA[4], mB[4], lB[4];
  f32x4 oA[4], oB[4];
#pragma unroll
  for (int i = 0; i < 4; ++i) {
    mA[i] = -1e30f; lA[i] = 0.f; oA[i] = zero4;
    mB[i] = -1e30f; lB[i] = 0.f; oB[i] = zero4;
  }

  // stage K/V tile jt into buffer bufi (4 global_load_lds per wave)
  auto issueKV = [&](int jt, int bufi) {
    const u16* kb = KB + (size_t)(jt * 64) * 1024;
#pragma unroll
    for (int g = 0; g < 2; ++g) {
      int p = g * 256 + tid;
      int row = p >> 3;
      int ss = (p & 7) ^ (row & 7);
      gload16(kb + (size_t)row * 1024 + ss * 8,
              (char*)(&Kt[bufi][0]) + (g * 256 + wv * 64) * 16);
    }
#pragma unroll
    for (int g = 0; g < 2; ++g) {
      int p = g * 256 + tid;
      int d = p >> 3;
      int ss = (p & 7) ^ (d & 7);
      gload16(VB + (size_t)d * 4096 + jt * 64 + ss * 8,
              (char*)(&Vl[bufi][0]) + (g * 256 + wv * 64) * 16);
    }
  };

  // one q-tile x kv-tile step: QK^T, online softmax, O += P V
  auto computeTile = [&](const u16* KtC, const u16* VlC, bool diag,
                         bf16x8 qf0, bf16x8 qf1,
                         float* m2, float* lsum, f32x4* oacc) {
    // S = Q K^T (Q pre-scaled -> log2 domain)
    f32x4 sf[4];
#pragma unroll
    for (int nt = 0; nt < 4; ++nt) {
      int row = nt * 16 + l15;
      int c0 = (l4 * 16) ^ ((row & 7) << 4);
      int c1 = (64 + l4 * 16) ^ ((row & 7) << 4);
      bf16x8 k0 = *(const bf16x8*)((const char*)KtC + row * 128 + c0);
      bf16x8 k1 = *(const bf16x8*)((const char*)KtC + row * 128 + c1);
      f32x4 s = zero4;
      s = __builtin_amdgcn_mfma_f32_16x16x32_bf16(qf0, k0, s, 0, 0, 0);
      s = __builtin_amdgcn_mfma_f32_16x16x32_bf16(qf1, k1, s, 0, 0, 0);
      sf[nt] = s;
    }

    float p4[4][4];
#pragma unroll
    for (int nt = 0; nt < 4; ++nt)
#pragma unroll
      for (int i = 0; i < 4; ++i) p4[nt][i] = sf[nt][i];
    if (diag) {
#pragma unroll
      for (int nt = 0; nt < 4; ++nt)
#pragma unroll
        for (int i = 0; i < 4; ++i)
          if (nt * 16 + l15 > wv * 16 + l4 * 4 + i) p4[nt][i] = -1e30f;
    }

    // online softmax (rows q = l4*4+i, kv spread over l15 and nt)
    float rm[4];
#pragma unroll
    for (int i = 0; i < 4; ++i)
      rm[i] = fmaxf(fmaxf(p4[0][i], p4[1][i]), fmaxf(p4[2][i], p4[3][i]));
#pragma unroll
    for (int d = 1; d < 16; d <<= 1)
#pragma unroll
      for (int i = 0; i < 4; ++i)
        rm[i] = fmaxf(rm[i], __shfl_xor(rm[i], d, 64));
    float cexp[4], rs[4];
#pragma unroll
    for (int i = 0; i < 4; ++i) {
      float mn = fmaxf(m2[i], rm[i]);
      cexp[i] = exp2f(m2[i] - mn);
      m2[i] = mn;
    }
#pragma unroll
    for (int nt = 0; nt < 4; ++nt)
#pragma unroll
      for (int i = 0; i < 4; ++i) p4[nt][i] = exp2f(p4[nt][i] - m2[i]);
#pragma unroll
    for (int i = 0; i < 4; ++i)
      rs[i] = (p4[0][i] + p4[1][i]) + (p4[2][i] + p4[3][i]);
#pragma unroll
    for (int d = 1; d < 16; d <<= 1)
#pragma unroll
      for (int i = 0; i < 4; ++i) rs[i] += __shfl_xor(rs[i], d, 64);
#pragma unroll
    for (int i = 0; i < 4; ++i) lsum[i] = lsum[i] * cexp[i] + rs[i];
#pragma unroll
    for (int nt = 0; nt < 4; ++nt)
#pragma unroll
      for (int i = 0; i < 4; ++i) oacc[nt][i] *= cexp[i];

    // P -> per-wave LDS (no barrier: Pl[wv] is wave-private)
#pragma unroll
    for (int nt = 0; nt < 4; ++nt)
#pragma unroll
      for (int i = 0; i < 4; ++i) {
        int r = l4 * 4 + i;
        int byt = r * 128 + ((nt * 32 + l15 * 2) ^ ((r & 7) << 4));
        *(u16*)((char*)Pl[wv] + byt) = f2bf(p4[nt][i]);
      }

    // O += P V
    bf16x8 pa0, pa1;
    {
      int r = l15;
      int c0 = (l4 * 16) ^ ((r & 7) << 4);
      int c1 = (64 + l4 * 16) ^ ((r & 7) << 4);
      pa0 = *(const bf16x8*)((const char*)Pl[wv] + r * 128 + c0);
      pa1 = *(const bf16x8*)((const char*)Pl[wv] + r * 128 + c1);
    }
#pragma unroll
    for (int nt = 0; nt < 4; ++nt) {
      int d = nt * 16 + l15;
      int c0 = (l4 * 16) ^ ((d & 7) << 4);
      int c1 = (64 + l4 * 16) ^ ((d & 7) << 4);
      bf16x8 v0 = *(const bf16x8*)((const char*)VlC + d * 128 + c0);
      bf16x8 v1 = *(const bf16x8*)((const char*)VlC + d * 128 + c1);
      oacc[nt] = __builtin_amdgcn_mfma_f32_16x16x32_bf16(pa0, v0, oacc[nt], 0, 0, 0);
      oacc[nt] = __builtin_amdgcn_mfma_f32_16x16x32_bf16(pa1, v1, oacc[nt], 0, 0, 0);
    }
  };

  issueKV(0, 0);  // prologue
  for (int j = 0; j < ntb; ++j) {
    const int cur = j & 1;
    __syncthreads();  // drains own vmcnt -> tile j fully in LDS; buf[1-cur] free
    if (j + 1 < ntb) issueKV(j + 1, 1 - cur);  // overlap with compute of j
    computeTile(&Kt[cur][0], &Vl[cur][0], j == qtB, qb0, qb1, mB, lB, oB);
    if (j < nta)
      computeTile(&Kt[cur][0], &Vl[cur][0], j == qtA, qa0, qa1, mA, lA, oA);
  }

  // normalize + store ctx (bf16, [b*2048+q][h*64+d])
  u16* ca = ctx + (size_t)(b * 2048 + qtA * 64 + wv * 16) * 1024 + h * 64;
  u16* cb = ctx + (size_t)(b * 2048 + qtB * 64 + wv * 16) * 1024 + h * 64;
#pragma unroll
  for (int i = 0; i < 4; ++i) {
    float iva = 1.f / lA[i];
    float ivb = 1.f / lB[i];
    int r = l4 * 4 + i;
#pragma unroll
    for (int nt = 0; nt < 4; ++nt) {
      ca[(size_t)r * 1024 + nt * 16 + l15] = f2bf(oA[nt][i] * iva);
      cb[(size_t)r * 1024 + nt * 16 + l15] = f2bf(oB[nt][i] * ivb);
    }
  }
}

// ---------------- launch ----------------
extern "C" void kernel_launch(void* const* d_in, const int* in_sizes, int n_in,
                              void* d_out, int out_size, void* d_ws,
                              size_t ws_size, hipStream_t stream) {
  const float* q  = (const float*)d_in[0];
  const float* k  = (const float*)d_in[1];
  const float* v  = (const float*)d_in[2];
  const float* Wq = (const float*)d_in[3];
  const float* bq = (const float*)d_in[4];
  const float* Wk = (const float*)d_in[5];
  const float* bk = (const float*)d_in[6];
  const float* Wv = (const float*)d_in[7];
  const float* bv = (const float*)d_in[8];
  const float* Wo = (const float*)d_in[9];
  const float* bo = (const float*)d_in[10];

  // workspace layout (40 MiB):
  //   [0,24M):   Xb = bf16(query|key|value), 3 x 4194304 elems
  //              (first 8 MiB reused later as ctx — Xb fully consumed first)
  //   [24M,32M): Wt = bf16 W^T for q,k,v,o, 4 x 1048576 elems
  //   [32M,40M): VtG = V^T bf16 [1024][4096]
  // d_out (16 MiB) doubles as scratch for Qb|Kb bf16 before the final GEMM
  // fully overwrites it (deterministic each call).
  char* ws = (char*)d_ws;
  u16* Xb  = (u16*)ws;
  u16* Wt  = (u16*)(ws + 25165824);
  u16* VtG = (u16*)(ws + 33554432);
  u16* ctx = Xb;
  u16* Qb  = (u16*)d_out;
  u16* Kb  = Qb + 4194304;

  // log2(e)/sqrt(2048): folded into Q so QK^T lands in exp2 domain
  const float SC2A = 0.0318793585f;

  cvt_qkv<<<dim3(2048, 3), 256, 0, stream>>>(q, k, v, Xb);
  trans_w<<<dim3(16, 16, 4), dim3(64, 8), 0, stream>>>(Wq, Wk, Wv, Wo, Wt);
  // Q,K projections (z-batched): C = (X @ W + b) * osc -> bf16
  gemm_bt<true, false><<<dim3(32, 8, 2), 256, 0, stream>>>(
      Xb, Wt, bq, bk, SC2A, 1.0f, (void*)Qb,
      4096, 1024, 1024, 4194304, 1048576, 4194304);
  // V^T = Wv^T . X^T (+bv per row) -> VtG[1024][4096]
  gemm_bt<true, true><<<dim3(8, 32, 1), 256, 0, stream>>>(
      Wt + 2 * 1048576, Xb + 2 * 4194304, bv, bv, 1.0f, 1.0f, (void*)VtG,
      1024, 4096, 1024, 0, 0, 0);
  attn_k<<<dim3(16, 32), 256, 0, stream>>>(Qb, Kb, VtG, ctx);
  // out = ctx @ Wo + bo -> fp32 d_out
  gemm_bt<false, false><<<dim3(32, 8, 1), 256, 0, stream>>>(
      ctx, Wt + 3 * 1048576, bo, bo, 1.0f, 1.0f, d_out,
      4096, 1024, 1024, 0, 0, 0);
}

// Round 3
// 142.022 us; speedup vs baseline: 1.3927x; 1.0981x over previous
//
#include <hip/hip_runtime.h>
#include <stdint.h>

typedef unsigned short u16;
typedef unsigned int u32;
typedef __bf16 bf16x8 __attribute__((ext_vector_type(8)));
typedef __bf16 bf16x4 __attribute__((ext_vector_type(4)));
typedef float f32x4 __attribute__((ext_vector_type(4)));

// fp32 -> bf16 round-to-nearest-even
__device__ __forceinline__ u16 f2bf(float f) {
  u32 u = __float_as_uint(f);
  u = (u + 0x7fffu + ((u >> 16) & 1u)) >> 16;
  return (u16)u;
}

// async global->LDS, 16B per lane; lds base must be wave-uniform (HW adds lane*16)
__device__ __forceinline__ void gload16(const void* g, void* l) {
  __builtin_amdgcn_global_load_lds(
      (const __attribute__((address_space(1))) void*)g,
      (__attribute__((address_space(3))) void*)l, 16, 0, 0);
}

// ---------------- fp32 -> bf16 convert (query/key/value) ----------------
__global__ __launch_bounds__(256) void cvt_qkv(
    const float* __restrict__ q, const float* __restrict__ k,
    const float* __restrict__ v, u16* __restrict__ dst) {
  const float* s = (blockIdx.y == 0) ? q : (blockIdx.y == 1) ? k : v;
  u16* d = dst + (size_t)blockIdx.y * 4194304u;
  int e = (blockIdx.x * 256 + threadIdx.x) * 8;
  float4 a = *(const float4*)(s + e);
  float4 b = *(const float4*)(s + e + 4);
  uint4 o;
  o.x = (u32)f2bf(a.x) | ((u32)f2bf(a.y) << 16);
  o.y = (u32)f2bf(a.z) | ((u32)f2bf(a.w) << 16);
  o.z = (u32)f2bf(b.x) | ((u32)f2bf(b.y) << 16);
  o.w = (u32)f2bf(b.z) | ((u32)f2bf(b.w) << 16);
  *(uint4*)(d + e) = o;
}

// ---------------- W [1024][1024] fp32 -> W^T bf16 ----------------
__global__ __launch_bounds__(512) void trans_w(
    const float* __restrict__ w0, const float* __restrict__ w1,
    const float* __restrict__ w2, const float* __restrict__ w3,
    u16* __restrict__ wt) {
  const float* W = (blockIdx.z == 0) ? w0 : (blockIdx.z == 1) ? w1
                   : (blockIdx.z == 2) ? w2 : w3;
  u16* Wt = wt + (size_t)blockIdx.z * 1048576u;
  __shared__ float tile[64][65];
  int x0 = blockIdx.x * 64, y0 = blockIdx.y * 64;
  int tx = threadIdx.x, ty = threadIdx.y;
#pragma unroll
  for (int j = 0; j < 8; ++j)
    tile[ty + j * 8][tx] = W[(size_t)(y0 + ty + j * 8) * 1024 + x0 + tx];
  __syncthreads();
#pragma unroll
  for (int j = 0; j < 8; ++j)
    Wt[(size_t)(x0 + ty + j * 8) * 1024 + y0 + tx] = f2bf(tile[tx][ty + j * 8]);
}

// ---------------- merged projection GEMM (Q, K, V^T) ----------------
// z=0: Qb = (Xq @ Wq + bq) * qsc        [4096][1024]
// z=1: Kb =  Xk @ Wk + bk               [4096][1024]
// z=2: VtG = (Wv^T . Xv^T) + bv(row)    [1024][4096]
// All operands bf16 row-major with row-length K=1024; 128x128 tiles, BK=64,
// 4 waves (2x2), LDS XOR-swizzle via pre-swizzled global source (rule #21).
__global__ __launch_bounds__(256, 2) void gemm_proj(
    const u16* __restrict__ Xb, const u16* __restrict__ Wt,
    const float* __restrict__ bqp, const float* __restrict__ bkp,
    const float* __restrict__ bvp,
    u16* __restrict__ Qb, u16* __restrict__ Kb, u16* __restrict__ VtG,
    float qsc) {
  const int z = blockIdx.z;
  const u16 *A, *Bt;
  const float* bias;
  u16* C;
  int N, bm, bn;
  float osc = 1.f;
  bool rowb = false;
  if (z < 2) {
    A = Xb + (size_t)z * 4194304u;
    Bt = Wt + (size_t)z * 1048576u;
    bias = z ? bkp : bqp;
    C = z ? Kb : Qb;
    N = 1024;
    bm = blockIdx.x * 128;
    bn = blockIdx.y * 128;
    if (z == 0) osc = qsc;
  } else {
    A = Wt + 2u * 1048576u;
    Bt = Xb + 2u * 4194304u;
    bias = bvp;
    C = VtG;
    N = 4096;
    bm = blockIdx.y * 128;   // M=1024 -> 8 tiles
    bn = blockIdx.x * 128;   // N=4096 -> 32 tiles
    rowb = true;
  }

  __shared__ __align__(16) u16 ldsA[128 * 64];
  __shared__ __align__(16) u16 ldsB[128 * 64];

  const int tid = threadIdx.x;
  const int lane = tid & 63, wv = tid >> 6;
  const int wr = wv >> 1, wc = wv & 1;
  const int l15 = lane & 15, l4 = lane >> 4;

  const f32x4 zero4 = {0.f, 0.f, 0.f, 0.f};
  f32x4 acc[4][4];
#pragma unroll
  for (int i = 0; i < 4; ++i)
#pragma unroll
    for (int j = 0; j < 4; ++j) acc[i][j] = zero4;

  for (int kt = 0; kt < 16; ++kt) {
    __syncthreads();
#pragma unroll
    for (int g = 0; g < 4; ++g) {
      int p = g * 256 + tid;
      int row = p >> 3;
      int ss = (p & 7) ^ (row & 7);
      gload16(A + (size_t)(bm + row) * 1024 + kt * 64 + ss * 8,
              (char*)ldsA + (g * 256 + wv * 64) * 16);
    }
#pragma unroll
    for (int g = 0; g < 4; ++g) {
      int p = g * 256 + tid;
      int row = p >> 3;
      int ss = (p & 7) ^ (row & 7);
      gload16(Bt + (size_t)(bn + row) * 1024 + kt * 64 + ss * 8,
              (char*)ldsB + (g * 256 + wv * 64) * 16);
    }
    __syncthreads();

    bf16x8 af[4][2], bfr[4][2];
#pragma unroll
    for (int mf = 0; mf < 4; ++mf) {
      int row = wr * 64 + mf * 16 + l15;
#pragma unroll
      for (int ks = 0; ks < 2; ++ks) {
        int byt = row * 128 + ((ks * 64 + l4 * 16) ^ ((row & 7) << 4));
        af[mf][ks] = *(const bf16x8*)((const char*)ldsA + byt);
      }
    }
#pragma unroll
    for (int nf = 0; nf < 4; ++nf) {
      int row = wc * 64 + nf * 16 + l15;
#pragma unroll
      for (int ks = 0; ks < 2; ++ks) {
        int byt = row * 128 + ((ks * 64 + l4 * 16) ^ ((row & 7) << 4));
        bfr[nf][ks] = *(const bf16x8*)((const char*)ldsB + byt);
      }
    }
#pragma unroll
    for (int mf = 0; mf < 4; ++mf)
#pragma unroll
      for (int nf = 0; nf < 4; ++nf) {
        acc[mf][nf] = __builtin_amdgcn_mfma_f32_16x16x32_bf16(
            af[mf][0], bfr[nf][0], acc[mf][nf], 0, 0, 0);
        acc[mf][nf] = __builtin_amdgcn_mfma_f32_16x16x32_bf16(
            af[mf][1], bfr[nf][1], acc[mf][nf], 0, 0, 0);
      }
  }

  float bcol[4];
  if (!rowb) {
#pragma unroll
    for (int nf = 0; nf < 4; ++nf)
      bcol[nf] = bias[bn + wc * 64 + nf * 16 + l15];
  }
#pragma unroll
  for (int mf = 0; mf < 4; ++mf) {
#pragma unroll
    for (int i = 0; i < 4; ++i) {
      int r = bm + wr * 64 + mf * 16 + l4 * 4 + i;
      float br = rowb ? bias[r] : 0.f;
#pragma unroll
      for (int nf = 0; nf < 4; ++nf) {
        int c = bn + wc * 64 + nf * 16 + l15;
        float val = (acc[mf][nf][i] + (rowb ? br : bcol[nf])) * osc;
        C[(size_t)r * N + c] = f2bf(val);
      }
    }
  }
}

// ---------------- final GEMM: out = ctx @ Wo^T' + bo (fp32) ----------------
__global__ __launch_bounds__(256, 2) void gemm_out(
    const u16* __restrict__ A, const u16* __restrict__ Bt,
    const float* __restrict__ bias, float* __restrict__ C) {
  __shared__ __align__(16) u16 ldsA[128 * 64];
  __shared__ __align__(16) u16 ldsB[128 * 64];

  const int tid = threadIdx.x;
  const int lane = tid & 63, wv = tid >> 6;
  const int wr = wv >> 1, wc = wv & 1;
  const int l15 = lane & 15, l4 = lane >> 4;
  const int bm = blockIdx.x * 128, bn = blockIdx.y * 128;

  const f32x4 zero4 = {0.f, 0.f, 0.f, 0.f};
  f32x4 acc[4][4];
#pragma unroll
  for (int i = 0; i < 4; ++i)
#pragma unroll
    for (int j = 0; j < 4; ++j) acc[i][j] = zero4;

  for (int kt = 0; kt < 16; ++kt) {
    __syncthreads();
#pragma unroll
    for (int g = 0; g < 4; ++g) {
      int p = g * 256 + tid;
      int row = p >> 3;
      int ss = (p & 7) ^ (row & 7);
      gload16(A + (size_t)(bm + row) * 1024 + kt * 64 + ss * 8,
              (char*)ldsA + (g * 256 + wv * 64) * 16);
    }
#pragma unroll
    for (int g = 0; g < 4; ++g) {
      int p = g * 256 + tid;
      int row = p >> 3;
      int ss = (p & 7) ^ (row & 7);
      gload16(Bt + (size_t)(bn + row) * 1024 + kt * 64 + ss * 8,
              (char*)ldsB + (g * 256 + wv * 64) * 16);
    }
    __syncthreads();

    bf16x8 af[4][2], bfr[4][2];
#pragma unroll
    for (int mf = 0; mf < 4; ++mf) {
      int row = wr * 64 + mf * 16 + l15;
#pragma unroll
      for (int ks = 0; ks < 2; ++ks) {
        int byt = row * 128 + ((ks * 64 + l4 * 16) ^ ((row & 7) << 4));
        af[mf][ks] = *(const bf16x8*)((const char*)ldsA + byt);
      }
    }
#pragma unroll
    for (int nf = 0; nf < 4; ++nf) {
      int row = wc * 64 + nf * 16 + l15;
#pragma unroll
      for (int ks = 0; ks < 2; ++ks) {
        int byt = row * 128 + ((ks * 64 + l4 * 16) ^ ((row & 7) << 4));
        bfr[nf][ks] = *(const bf16x8*)((const char*)ldsB + byt);
      }
    }
#pragma unroll
    for (int mf = 0; mf < 4; ++mf)
#pragma unroll
      for (int nf = 0; nf < 4; ++nf) {
        acc[mf][nf] = __builtin_amdgcn_mfma_f32_16x16x32_bf16(
            af[mf][0], bfr[nf][0], acc[mf][nf], 0, 0, 0);
        acc[mf][nf] = __builtin_amdgcn_mfma_f32_16x16x32_bf16(
            af[mf][1], bfr[nf][1], acc[mf][nf], 0, 0, 0);
      }
  }

  float bcol[4];
#pragma unroll
  for (int nf = 0; nf < 4; ++nf)
    bcol[nf] = bias[bn + wc * 64 + nf * 16 + l15];
#pragma unroll
  for (int mf = 0; mf < 4; ++mf) {
#pragma unroll
    for (int i = 0; i < 4; ++i) {
      int r = bm + wr * 64 + mf * 16 + l4 * 4 + i;
#pragma unroll
      for (int nf = 0; nf < 4; ++nf) {
        int c = bn + wc * 64 + nf * 16 + l15;
        C[(size_t)r * 1024 + c] = acc[mf][nf][i] + bcol[nf];
      }
    }
  }
}

// ---------------- causal flash attention (swapped QK^T) ----------------
// Q,K: [B*S][1024] bf16 (head h at cols h*64..+63). Q pre-scaled by
// log2(e)/sqrt(2048). Vt: [h*64+d][B*S] bf16.
// Grid (32,32): one q-tile (64 rows) per block, qt = 31-bx (longest first).
// 4 waves x 16 q-rows. KVBLK=64, double-buffered K/V staging, 1 barrier/tile.
// QK^T computed swapped (mfma(K,Q)) so softmax rows are near-lane-local:
// lane (l15=q, l4) holds kv = nt*16+l4*4+i -> reduce = in-reg 16 + 2 shfl.
__global__ __launch_bounds__(256, 4) void attn_k(
    const u16* __restrict__ Q, const u16* __restrict__ Kb,
    const u16* __restrict__ Vt, u16* __restrict__ ctx) {
  const int qt = 31 - blockIdx.x;
  const int bh = blockIdx.y;
  const int b = bh >> 4, h = bh & 15;
  const int tid = threadIdx.x;
  const int lane = tid & 63, wv = tid >> 6;
  const int l15 = lane & 15, l4 = lane >> 4;

  __shared__ __align__(16) u16 Kt[2][64 * 64];   // [kv][d], swizzled
  __shared__ __align__(16) u16 Vl[2][64 * 64];   // [d][kv], swizzled
  __shared__ __align__(16) u16 Pl[4][16 * 64];   // per-wave P [q][kv], swizzled

  const u16* KB = Kb + (size_t)(b * 2048) * 1024 + h * 64;
  const u16* VB = Vt + (size_t)(h * 64) * 4096 + b * 2048;

  const u16* qp =
      Q + (size_t)(b * 2048 + qt * 64 + wv * 16 + l15) * 1024 + h * 64;
  bf16x8 qf0 = *(const bf16x8*)(qp + l4 * 8);
  bf16x8 qf1 = *(const bf16x8*)(qp + 32 + l4 * 8);

  const f32x4 zero4 = {0.f, 0.f, 0.f, 0.f};
  f32x4 oacc[4];  // [nt]: O[q=l4*4+i][d=nt*16+l15]
#pragma unroll
  for (int i = 0; i < 4; ++i) oacc[i] = zero4;
  float m = -1e30f, lsum = 0.f;  // per-lane softmax state for q = l15

  auto issueKV = [&](int jt, int bufi) {
    const u16* kb = KB + (size_t)(jt * 64) * 1024;
#pragma unroll
    for (int g = 0; g < 2; ++g) {
      int p = g * 256 + tid;
      int row = p >> 3;
      int ss = (p & 7) ^ (row & 7);
      gload16(kb + (size_t)row * 1024 + ss * 8,
              (char*)(&Kt[bufi][0]) + (g * 256 + wv * 64) * 16);
    }
#pragma unroll
    for (int g = 0; g < 2; ++g) {
      int p = g * 256 + tid;
      int d = p >> 3;
      int ss = (p & 7) ^ (d & 7);
      gload16(VB + (size_t)d * 4096 + jt * 64 + ss * 8,
              (char*)(&Vl[bufi][0]) + (g * 256 + wv * 64) * 16);
    }
  };

  issueKV(0, 0);
  for (int j = 0; j <= qt; ++j) {
    const int cur = j & 1;
    __syncthreads();  // own-vmcnt drain -> tile j in LDS; frees other buffer
    if (j < qt) issueKV(j + 1, cur ^ 1);

    // S^T tiles: rows kv, cols q  (A = K-frag, B = Q-frag)
    f32x4 p4[4];
    __builtin_amdgcn_s_setprio(1);
#pragma unroll
    for (int nt = 0; nt < 4; ++nt) {
      int row = nt * 16 + l15;
      int sw = (row & 7) << 4;
      bf16x8 k0 =
          *(const bf16x8*)((const char*)&Kt[cur][0] + row * 128 + ((l4 * 16) ^ sw));
      bf16x8 k1 = *(const bf16x8*)((const char*)&Kt[cur][0] + row * 128 +
                                   ((64 + l4 * 16) ^ sw));
      f32x4 s = zero4;
      s = __builtin_amdgcn_mfma_f32_16x16x32_bf16(k0, qf0, s, 0, 0, 0);
      s = __builtin_amdgcn_mfma_f32_16x16x32_bf16(k1, qf1, s, 0, 0, 0);
      p4[nt] = s;
    }
    __builtin_amdgcn_s_setprio(0);

    if (j == qt) {  // causal mask on diagonal tile: kv_local > q_local
#pragma unroll
      for (int nt = 0; nt < 4; ++nt)
#pragma unroll
        for (int i = 0; i < 4; ++i)
          if (nt * 16 + l4 * 4 + i > wv * 16 + l15) p4[nt][i] = -1e30f;
    }

    // row max: 16 in-register + 2 cross-lane steps (l4 dim)
    float rm = p4[0][0];
#pragma unroll
    for (int nt = 0; nt < 4; ++nt)
#pragma unroll
      for (int i = 0; i < 4; ++i) rm = fmaxf(rm, p4[nt][i]);
    rm = fmaxf(rm, __shfl_xor(rm, 16, 64));
    rm = fmaxf(rm, __shfl_xor(rm, 32, 64));

    // defer-max (THR=8 in log2 domain): rescale only when max grew
    if (!__all(rm - m <= 8.0f)) {
      float mn = fmaxf(m, rm);
      float ce = exp2f(m - mn);
      m = mn;
      lsum *= ce;
#pragma unroll
      for (int i = 0; i < 4; ++i) {
        float cei = __shfl(ce, (lane & 48) | (l4 * 4 + i), 64);
#pragma unroll
        for (int nt = 0; nt < 4; ++nt) oacc[nt][i] *= cei;
      }
    }

    // P = exp2(S - m), row-sum
    float rs = 0.f;
#pragma unroll
    for (int nt = 0; nt < 4; ++nt)
#pragma unroll
      for (int i = 0; i < 4; ++i) {
        float e = exp2f(p4[nt][i] - m);
        p4[nt][i] = e;
        rs += e;
      }
    rs += __shfl_xor(rs, 16, 64);
    rs += __shfl_xor(rs, 32, 64);
    lsum += rs;

    // P -> Pl[wv] as [q=16][kv=64] bf16: 4 x ds_write_b64 (kv contiguous)
    {
      int sw = (l15 & 7) << 4;
#pragma unroll
      for (int nt = 0; nt < 4; ++nt) {
        bf16x4 pb = __builtin_convertvector(p4[nt], bf16x4);
        *(bf16x4*)((char*)&Pl[wv][0] + l15 * 128 + ((nt * 32 + l4 * 8) ^ sw)) = pb;
      }
    }

    // O += P V
    bf16x8 pa0, pa1;
    {
      int sw = (l15 & 7) << 4;
      pa0 = *(const bf16x8*)((const char*)&Pl[wv][0] + l15 * 128 + ((l4 * 16) ^ sw));
      pa1 = *(const bf16x8*)((const char*)&Pl[wv][0] + l15 * 128 +
                             ((64 + l4 * 16) ^ sw));
    }
    __builtin_amdgcn_s_setprio(1);
#pragma unroll
    for (int nt = 0; nt < 4; ++nt) {
      int d = nt * 16 + l15;
      int sw = (d & 7) << 4;
      bf16x8 v0 =
          *(const bf16x8*)((const char*)&Vl[cur][0] + d * 128 + ((l4 * 16) ^ sw));
      bf16x8 v1 = *(const bf16x8*)((const char*)&Vl[cur][0] + d * 128 +
                                   ((64 + l4 * 16) ^ sw));
      oacc[nt] = __builtin_amdgcn_mfma_f32_16x16x32_bf16(pa0, v0, oacc[nt], 0, 0, 0);
      oacc[nt] = __builtin_amdgcn_mfma_f32_16x16x32_bf16(pa1, v1, oacc[nt], 0, 0, 0);
    }
    __builtin_amdgcn_s_setprio(0);
  }

  // normalize + store ctx (bf16, [b*2048+q][h*64+d])
  float rcp = 1.f / lsum;
  u16* cb = ctx + (size_t)(b * 2048 + qt * 64 + wv * 16) * 1024 + h * 64;
#pragma unroll
  for (int i = 0; i < 4; ++i) {
    float iv = __shfl(rcp, (lane & 48) | (l4 * 4 + i), 64);
    int r = l4 * 4 + i;
#pragma unroll
    for (int nt = 0; nt < 4; ++nt)
      cb[(size_t)r * 1024 + nt * 16 + l15] = f2bf(oacc[nt][i] * iv);
  }
}

// ---------------- launch ----------------
extern "C" void kernel_launch(void* const* d_in, const int* in_sizes, int n_in,
                              void* d_out, int out_size, void* d_ws,
                              size_t ws_size, hipStream_t stream) {
  const float* q  = (const float*)d_in[0];
  const float* k  = (const float*)d_in[1];
  const float* v  = (const float*)d_in[2];
  const float* Wq = (const float*)d_in[3];
  const float* bq = (const float*)d_in[4];
  const float* Wk = (const float*)d_in[5];
  const float* bk = (const float*)d_in[6];
  const float* Wv = (const float*)d_in[7];
  const float* bv = (const float*)d_in[8];
  const float* Wo = (const float*)d_in[9];
  const float* bo = (const float*)d_in[10];

  // workspace layout (40 MiB):
  //   [0,24M):   Xb = bf16(query|key|value); first 8 MiB reused later as ctx
  //   [24M,32M): Wt = bf16 W^T for q,k,v,o
  //   [32M,40M): VtG = V^T bf16 [1024][4096]
  // d_out (16 MiB) doubles as Qb|Kb bf16 scratch until the final GEMM
  // fully overwrites it with fp32 output (deterministic each call).
  char* ws = (char*)d_ws;
  u16* Xb  = (u16*)ws;
  u16* Wt  = (u16*)(ws + 25165824);
  u16* VtG = (u16*)(ws + 33554432);
  u16* ctx = Xb;
  u16* Qb  = (u16*)d_out;
  u16* Kb  = Qb + 4194304;

  const float SC2A = 0.0318793585f;  // log2(e)/sqrt(2048), folded into Q

  cvt_qkv<<<dim3(2048, 3), 256, 0, stream>>>(q, k, v, Xb);
  trans_w<<<dim3(16, 16, 4), dim3(64, 8), 0, stream>>>(Wq, Wk, Wv, Wo, Wt);
  gemm_proj<<<dim3(32, 8, 3), 256, 0, stream>>>(Xb, Wt, bq, bk, bv, Qb, Kb,
                                                VtG, SC2A);
  attn_k<<<dim3(32, 32), 256, 0, stream>>>(Qb, Kb, VtG, ctx);
  gemm_out<<<dim3(32, 8), 256, 0, stream>>>(ctx, Wt + 3 * 1048576, bo,
                                            (float*)d_out);
}

// Round 4
// 121.042 us; speedup vs baseline: 1.6341x; 1.1733x over previous
//
#include <hip/hip_runtime.h>
#include <stdint.h>

typedef unsigned short u16;
typedef unsigned int u32;
typedef __bf16 bf16x8 __attribute__((ext_vector_type(8)));
typedef __bf16 bf16x4 __attribute__((ext_vector_type(4)));
typedef float f32x4 __attribute__((ext_vector_type(4)));

// fp32 -> bf16 round-to-nearest-even
__device__ __forceinline__ u16 f2bf(float f) {
  u32 u = __float_as_uint(f);
  u = (u + 0x7fffu + ((u >> 16) & 1u)) >> 16;
  return (u16)u;
}

// async global->LDS, 16B per lane; lds base must be wave-uniform (HW adds lane*16)
__device__ __forceinline__ void gload16(const void* g, void* l) {
  __builtin_amdgcn_global_load_lds(
      (const __attribute__((address_space(1))) void*)g,
      (__attribute__((address_space(3))) void*)l, 16, 0, 0);
}

// ---------------- fp32 -> bf16 convert (query/key/value) ----------------
__global__ __launch_bounds__(256) void cvt_qkv(
    const float* __restrict__ q, const float* __restrict__ k,
    const float* __restrict__ v, u16* __restrict__ dst) {
  const float* s = (blockIdx.y == 0) ? q : (blockIdx.y == 1) ? k : v;
  u16* d = dst + (size_t)blockIdx.y * 4194304u;
  int e = (blockIdx.x * 256 + threadIdx.x) * 8;
  float4 a = *(const float4*)(s + e);
  float4 b = *(const float4*)(s + e + 4);
  uint4 o;
  o.x = (u32)f2bf(a.x) | ((u32)f2bf(a.y) << 16);
  o.y = (u32)f2bf(a.z) | ((u32)f2bf(a.w) << 16);
  o.z = (u32)f2bf(b.x) | ((u32)f2bf(b.y) << 16);
  o.w = (u32)f2bf(b.z) | ((u32)f2bf(b.w) << 16);
  *(uint4*)(d + e) = o;
}

// ---------------- W [1024][1024] fp32 -> W^T bf16 ----------------
__global__ __launch_bounds__(512) void trans_w(
    const float* __restrict__ w0, const float* __restrict__ w1,
    const float* __restrict__ w2, const float* __restrict__ w3,
    u16* __restrict__ wt) {
  const float* W = (blockIdx.z == 0) ? w0 : (blockIdx.z == 1) ? w1
                   : (blockIdx.z == 2) ? w2 : w3;
  u16* Wt = wt + (size_t)blockIdx.z * 1048576u;
  __shared__ float tile[64][65];
  int x0 = blockIdx.x * 64, y0 = blockIdx.y * 64;
  int tx = threadIdx.x, ty = threadIdx.y;
#pragma unroll
  for (int j = 0; j < 8; ++j)
    tile[ty + j * 8][tx] = W[(size_t)(y0 + ty + j * 8) * 1024 + x0 + tx];
  __syncthreads();
#pragma unroll
  for (int j = 0; j < 8; ++j)
    Wt[(size_t)(x0 + ty + j * 8) * 1024 + y0 + tx] = f2bf(tile[tx][ty + j * 8]);
}

// ---------------- merged projection GEMM (Q, K, V^T) ----------------
// z=0: Qb = (Xq @ Wq + bq) * qsc        [4096][1024]
// z=1: Kb =  Xk @ Wk + bk               [4096][1024]
// z=2: VtG = (Wv^T . Xv^T) + bv(row)    [1024][4096]
__global__ __launch_bounds__(256, 2) void gemm_proj(
    const u16* __restrict__ Xb, const u16* __restrict__ Wt,
    const float* __restrict__ bqp, const float* __restrict__ bkp,
    const float* __restrict__ bvp,
    u16* __restrict__ Qb, u16* __restrict__ Kb, u16* __restrict__ VtG,
    float qsc) {
  const int z = blockIdx.z;
  const u16 *A, *Bt;
  const float* bias;
  u16* C;
  int N, bm, bn;
  float osc = 1.f;
  bool rowb = false;
  if (z < 2) {
    A = Xb + (size_t)z * 4194304u;
    Bt = Wt + (size_t)z * 1048576u;
    bias = z ? bkp : bqp;
    C = z ? Kb : Qb;
    N = 1024;
    bm = blockIdx.x * 128;
    bn = blockIdx.y * 128;
    if (z == 0) osc = qsc;
  } else {
    A = Wt + 2u * 1048576u;
    Bt = Xb + 2u * 4194304u;
    bias = bvp;
    C = VtG;
    N = 4096;
    bm = blockIdx.y * 128;
    bn = blockIdx.x * 128;
    rowb = true;
  }

  __shared__ __align__(16) u16 ldsA[128 * 64];
  __shared__ __align__(16) u16 ldsB[128 * 64];

  const int tid = threadIdx.x;
  const int lane = tid & 63, wv = tid >> 6;
  const int wr = wv >> 1, wc = wv & 1;
  const int l15 = lane & 15, l4 = lane >> 4;

  const f32x4 zero4 = {0.f, 0.f, 0.f, 0.f};
  f32x4 acc[4][4];
#pragma unroll
  for (int i = 0; i < 4; ++i)
#pragma unroll
    for (int j = 0; j < 4; ++j) acc[i][j] = zero4;

  for (int kt = 0; kt < 16; ++kt) {
    __syncthreads();
#pragma unroll
    for (int g = 0; g < 4; ++g) {
      int p = g * 256 + tid;
      int row = p >> 3;
      int ss = (p & 7) ^ (row & 7);
      gload16(A + (size_t)(bm + row) * 1024 + kt * 64 + ss * 8,
              (char*)ldsA + (g * 256 + wv * 64) * 16);
    }
#pragma unroll
    for (int g = 0; g < 4; ++g) {
      int p = g * 256 + tid;
      int row = p >> 3;
      int ss = (p & 7) ^ (row & 7);
      gload16(Bt + (size_t)(bn + row) * 1024 + kt * 64 + ss * 8,
              (char*)ldsB + (g * 256 + wv * 64) * 16);
    }
    __syncthreads();

    bf16x8 af[4][2], bfr[4][2];
#pragma unroll
    for (int mf = 0; mf < 4; ++mf) {
      int row = wr * 64 + mf * 16 + l15;
#pragma unroll
      for (int ks = 0; ks < 2; ++ks) {
        int byt = row * 128 + ((ks * 64 + l4 * 16) ^ ((row & 7) << 4));
        af[mf][ks] = *(const bf16x8*)((const char*)ldsA + byt);
      }
    }
#pragma unroll
    for (int nf = 0; nf < 4; ++nf) {
      int row = wc * 64 + nf * 16 + l15;
#pragma unroll
      for (int ks = 0; ks < 2; ++ks) {
        int byt = row * 128 + ((ks * 64 + l4 * 16) ^ ((row & 7) << 4));
        bfr[nf][ks] = *(const bf16x8*)((const char*)ldsB + byt);
      }
    }
#pragma unroll
    for (int mf = 0; mf < 4; ++mf)
#pragma unroll
      for (int nf = 0; nf < 4; ++nf) {
        acc[mf][nf] = __builtin_amdgcn_mfma_f32_16x16x32_bf16(
            af[mf][0], bfr[nf][0], acc[mf][nf], 0, 0, 0);
        acc[mf][nf] = __builtin_amdgcn_mfma_f32_16x16x32_bf16(
            af[mf][1], bfr[nf][1], acc[mf][nf], 0, 0, 0);
      }
  }

  float bcol[4];
  if (!rowb) {
#pragma unroll
    for (int nf = 0; nf < 4; ++nf)
      bcol[nf] = bias[bn + wc * 64 + nf * 16 + l15];
  }
#pragma unroll
  for (int mf = 0; mf < 4; ++mf) {
#pragma unroll
    for (int i = 0; i < 4; ++i) {
      int r = bm + wr * 64 + mf * 16 + l4 * 4 + i;
      float br = rowb ? bias[r] : 0.f;
#pragma unroll
      for (int nf = 0; nf < 4; ++nf) {
        int c = bn + wc * 64 + nf * 16 + l15;
        float val = (acc[mf][nf][i] + (rowb ? br : bcol[nf])) * osc;
        C[(size_t)r * N + c] = f2bf(val);
      }
    }
  }
}

// ---------------- final GEMM: out = ctx @ Wo^T' + bo (fp32) ----------------
__global__ __launch_bounds__(256, 2) void gemm_out(
    const u16* __restrict__ A, const u16* __restrict__ Bt,
    const float* __restrict__ bias, float* __restrict__ C) {
  __shared__ __align__(16) u16 ldsA[128 * 64];
  __shared__ __align__(16) u16 ldsB[128 * 64];

  const int tid = threadIdx.x;
  const int lane = tid & 63, wv = tid >> 6;
  const int wr = wv >> 1, wc = wv & 1;
  const int l15 = lane & 15, l4 = lane >> 4;
  const int bm = blockIdx.x * 128, bn = blockIdx.y * 128;

  const f32x4 zero4 = {0.f, 0.f, 0.f, 0.f};
  f32x4 acc[4][4];
#pragma unroll
  for (int i = 0; i < 4; ++i)
#pragma unroll
    for (int j = 0; j < 4; ++j) acc[i][j] = zero4;

  for (int kt = 0; kt < 16; ++kt) {
    __syncthreads();
#pragma unroll
    for (int g = 0; g < 4; ++g) {
      int p = g * 256 + tid;
      int row = p >> 3;
      int ss = (p & 7) ^ (row & 7);
      gload16(A + (size_t)(bm + row) * 1024 + kt * 64 + ss * 8,
              (char*)ldsA + (g * 256 + wv * 64) * 16);
    }
#pragma unroll
    for (int g = 0; g < 4; ++g) {
      int p = g * 256 + tid;
      int row = p >> 3;
      int ss = (p & 7) ^ (row & 7);
      gload16(Bt + (size_t)(bn + row) * 1024 + kt * 64 + ss * 8,
              (char*)ldsB + (g * 256 + wv * 64) * 16);
    }
    __syncthreads();

    bf16x8 af[4][2], bfr[4][2];
#pragma unroll
    for (int mf = 0; mf < 4; ++mf) {
      int row = wr * 64 + mf * 16 + l15;
#pragma unroll
      for (int ks = 0; ks < 2; ++ks) {
        int byt = row * 128 + ((ks * 64 + l4 * 16) ^ ((row & 7) << 4));
        af[mf][ks] = *(const bf16x8*)((const char*)ldsA + byt);
      }
    }
#pragma unroll
    for (int nf = 0; nf < 4; ++nf) {
      int row = wc * 64 + nf * 16 + l15;
#pragma unroll
      for (int ks = 0; ks < 2; ++ks) {
        int byt = row * 128 + ((ks * 64 + l4 * 16) ^ ((row & 7) << 4));
        bfr[nf][ks] = *(const bf16x8*)((const char*)ldsB + byt);
      }
    }
#pragma unroll
    for (int mf = 0; mf < 4; ++mf)
#pragma unroll
      for (int nf = 0; nf < 4; ++nf) {
        acc[mf][nf] = __builtin_amdgcn_mfma_f32_16x16x32_bf16(
            af[mf][0], bfr[nf][0], acc[mf][nf], 0, 0, 0);
        acc[mf][nf] = __builtin_amdgcn_mfma_f32_16x16x32_bf16(
            af[mf][1], bfr[nf][1], acc[mf][nf], 0, 0, 0);
      }
  }

  float bcol[4];
#pragma unroll
  for (int nf = 0; nf < 4; ++nf)
    bcol[nf] = bias[bn + wc * 64 + nf * 16 + l15];
#pragma unroll
  for (int mf = 0; mf < 4; ++mf) {
#pragma unroll
    for (int i = 0; i < 4; ++i) {
      int r = bm + wr * 64 + mf * 16 + l4 * 4 + i;
#pragma unroll
      for (int nf = 0; nf < 4; ++nf) {
        int c = bn + wc * 64 + nf * 16 + l15;
        C[(size_t)r * 1024 + c] = acc[mf][nf][i] + bcol[nf];
      }
    }
  }
}

// ---------------- causal flash attention (swapped QK^T, KVBLK=128) --------
// Q,K: [B*S][1024] bf16 (head h at cols h*64..+63), Q pre-scaled by
// log2(e)/sqrt(2048). Vt: [h*64+d][B*S] bf16.
// XCD-pinned remap: id%8 = XCD slot; each XCD owns 4 bh columns entirely
// (K/V working set 4 x 512KB = 2MB < 4MB L2/XCD). qt descending per column.
// 4 waves x 16 q-rows; KVBLK=128 (2 kv-tiles per barrier, one softmax pass).
__global__ __launch_bounds__(256, 2) void attn_k(
    const u16* __restrict__ Q, const u16* __restrict__ Kb,
    const u16* __restrict__ Vt, u16* __restrict__ ctx) {
  const int id = blockIdx.x + (blockIdx.y << 5);
  const int xcd = id & 7;
  const int kk = id >> 3;               // 0..127
  const int bh = xcd * 4 + (kk & 3);    // 4 bh columns per XCD
  const int qt = 31 - (kk >> 2);        // longest first within column
  const int b = bh >> 4, h = bh & 15;
  const int tid = threadIdx.x;
  const int lane = tid & 63, wv = tid >> 6;
  const int l15 = lane & 15, l4 = lane >> 4;

  __shared__ __align__(16) u16 Kt[2][128 * 64];   // [kv][d], swizzled (16KB ea)
  __shared__ __align__(16) u16 Vl[2][64 * 128];   // [d][kv], swizzled (16KB ea)
  __shared__ __align__(16) u16 Pl[4][16 * 128];   // per-wave P [q][kv] (4KB ea)

  const u16* KB = Kb + (size_t)(b * 2048) * 1024 + h * 64;
  const u16* VB = Vt + (size_t)(h * 64) * 4096 + b * 2048;

  const u16* qp =
      Q + (size_t)(b * 2048 + qt * 64 + wv * 16 + l15) * 1024 + h * 64;
  bf16x8 qf0 = *(const bf16x8*)(qp + l4 * 8);
  bf16x8 qf1 = *(const bf16x8*)(qp + 32 + l4 * 8);

  const f32x4 zero4 = {0.f, 0.f, 0.f, 0.f};
  f32x4 oacc[4];  // [ntd]: O[q=l4*4+i][d=ntd*16+l15]
#pragma unroll
  for (int i = 0; i < 4; ++i) oacc[i] = zero4;
  float m = -1e30f, lsum = 0.f;  // per-lane softmax state for q = l15

  // stage 128-kv tile jt: K 128x64 (128B rows), V 64x128 (256B rows)
  auto issueKV = [&](int jt, int bufi) {
    const u16* kb = KB + (size_t)(jt * 128) * 1024;
#pragma unroll
    for (int g = 0; g < 4; ++g) {
      int p = g * 256 + tid;
      int row = p >> 3;
      int ss = (p & 7) ^ (row & 7);
      gload16(kb + (size_t)row * 1024 + ss * 8,
              (char*)(&Kt[bufi][0]) + (g * 256 + wv * 64) * 16);
    }
#pragma unroll
    for (int g = 0; g < 4; ++g) {
      int p = g * 256 + tid;
      int row = p >> 4;
      int ss = (p & 15) ^ (row & 7);
      gload16(VB + (size_t)row * 4096 + jt * 128 + ss * 8,
              (char*)(&Vl[bufi][0]) + (g * 256 + wv * 64) * 16);
    }
  };

  const int nIter = (qt >> 1) + 1;
  const int qg = qt * 64 + wv * 16 + l15;  // this lane's q row (as softmax col)

  issueKV(0, 0);
  for (int it = 0; it < nIter; ++it) {
    const int cur = it & 1;
    __syncthreads();  // own-vmcnt drain: tile it resident; other buffer free
    if (it + 1 < nIter) issueKV(it + 1, cur ^ 1);

    // S^T: rows kv (8 x 16), cols q
    f32x4 p4[8];
    __builtin_amdgcn_s_setprio(1);
#pragma unroll
    for (int nt = 0; nt < 8; ++nt) {
      int row = nt * 16 + l15;
      int sw = (row & 7) << 4;
      bf16x8 k0 =
          *(const bf16x8*)((const char*)&Kt[cur][0] + row * 128 + ((l4 * 16) ^ sw));
      bf16x8 k1 = *(const bf16x8*)((const char*)&Kt[cur][0] + row * 128 +
                                   ((64 + l4 * 16) ^ sw));
      f32x4 s = zero4;
      s = __builtin_amdgcn_mfma_f32_16x16x32_bf16(k0, qf0, s, 0, 0, 0);
      s = __builtin_amdgcn_mfma_f32_16x16x32_bf16(k1, qf1, s, 0, 0, 0);
      p4[nt] = s;
    }
    __builtin_amdgcn_s_setprio(0);

    if (it == nIter - 1) {  // causal mask (covers both halves)
      int kvb = it * 128;
#pragma unroll
      for (int nt = 0; nt < 8; ++nt)
#pragma unroll
        for (int i = 0; i < 4; ++i)
          if (kvb + nt * 16 + l4 * 4 + i > qg) p4[nt][i] = -1e30f;
    }

    // row max: in-register tree over 32 + 2 cross-lane steps
    float mx[8];
#pragma unroll
    for (int nt = 0; nt < 8; ++nt)
      mx[nt] = fmaxf(fmaxf(p4[nt][0], p4[nt][1]), fmaxf(p4[nt][2], p4[nt][3]));
    float rm = fmaxf(fmaxf(fmaxf(mx[0], mx[1]), fmaxf(mx[2], mx[3])),
                     fmaxf(fmaxf(mx[4], mx[5]), fmaxf(mx[6], mx[7])));
    rm = fmaxf(rm, __shfl_xor(rm, 16, 64));
    rm = fmaxf(rm, __shfl_xor(rm, 32, 64));

    // defer-max (THR=8 in log2 domain)
    if (!__all(rm - m <= 8.0f)) {
      float mn = fmaxf(m, rm);
      float ce = exp2f(m - mn);
      m = mn;
      lsum *= ce;
#pragma unroll
      for (int i = 0; i < 4; ++i) {
        float cei = __shfl(ce, (lane & 48) | (l4 * 4 + i), 64);
#pragma unroll
        for (int nt = 0; nt < 4; ++nt) oacc[nt][i] *= cei;
      }
    }

    // P = exp2(S - m), row-sum
    float rs = 0.f;
#pragma unroll
    for (int nt = 0; nt < 8; ++nt) {
      float s0 = 0.f;
#pragma unroll
      for (int i = 0; i < 4; ++i) {
        float e = exp2f(p4[nt][i] - m);
        p4[nt][i] = e;
        s0 += e;
      }
      rs += s0;
    }
    rs += __shfl_xor(rs, 16, 64);
    rs += __shfl_xor(rs, 32, 64);
    lsum += rs;

    // P -> Pl[wv] as [q=16][kv=128] bf16 (8 x ds_write_b64, swizzled)
    const int swp = (l15 & 7) << 4;
#pragma unroll
    for (int nt = 0; nt < 8; ++nt) {
      bf16x4 pb = __builtin_convertvector(p4[nt], bf16x4);
      *(bf16x4*)((char*)&Pl[wv][0] + l15 * 256 + ((nt * 32 + l4 * 8) ^ swp)) = pb;
    }

    // O += P V  (4 kv-chunks of 32)
    bf16x8 pa[4];
#pragma unroll
    for (int c = 0; c < 4; ++c)
      pa[c] = *(const bf16x8*)((const char*)&Pl[wv][0] + l15 * 256 +
                               ((c * 64 + l4 * 16) ^ swp));
    __builtin_amdgcn_s_setprio(1);
#pragma unroll
    for (int ntd = 0; ntd < 4; ++ntd) {
      int d = ntd * 16 + l15;
      int sw = (d & 7) << 4;
#pragma unroll
      for (int c = 0; c < 4; ++c) {
        bf16x8 vv = *(const bf16x8*)((const char*)&Vl[cur][0] + d * 256 +
                                     ((c * 64 + l4 * 16) ^ sw));
        oacc[ntd] =
            __builtin_amdgcn_mfma_f32_16x16x32_bf16(pa[c], vv, oacc[ntd], 0, 0, 0);
      }
    }
    __builtin_amdgcn_s_setprio(0);
  }

  // normalize + store ctx (bf16, [b*2048+q][h*64+d])
  float rcp = 1.f / lsum;
  u16* cb = ctx + (size_t)(b * 2048 + qt * 64 + wv * 16) * 1024 + h * 64;
#pragma unroll
  for (int i = 0; i < 4; ++i) {
    float iv = __shfl(rcp, (lane & 48) | (l4 * 4 + i), 64);
    int r = l4 * 4 + i;
#pragma unroll
    for (int nt = 0; nt < 4; ++nt)
      cb[(size_t)r * 1024 + nt * 16 + l15] = f2bf(oacc[nt][i] * iv);
  }
}

// ---------------- launch ----------------
extern "C" void kernel_launch(void* const* d_in, const int* in_sizes, int n_in,
                              void* d_out, int out_size, void* d_ws,
                              size_t ws_size, hipStream_t stream) {
  const float* q  = (const float*)d_in[0];
  const float* k  = (const float*)d_in[1];
  const float* v  = (const float*)d_in[2];
  const float* Wq = (const float*)d_in[3];
  const float* bq = (const float*)d_in[4];
  const float* Wk = (const float*)d_in[5];
  const float* bk = (const float*)d_in[6];
  const float* Wv = (const float*)d_in[7];
  const float* bv = (const float*)d_in[8];
  const float* Wo = (const float*)d_in[9];
  const float* bo = (const float*)d_in[10];

  // workspace layout (40 MiB):
  //   [0,24M):   Xb = bf16(query|key|value); first 8 MiB reused later as ctx
  //   [24M,32M): Wt = bf16 W^T for q,k,v,o
  //   [32M,40M): VtG = V^T bf16 [1024][4096]
  // d_out (16 MiB) doubles as Qb|Kb bf16 scratch until the final GEMM
  // fully overwrites it with fp32 output (deterministic each call).
  char* ws = (char*)d_ws;
  u16* Xb  = (u16*)ws;
  u16* Wt  = (u16*)(ws + 25165824);
  u16* VtG = (u16*)(ws + 33554432);
  u16* ctx = Xb;
  u16* Qb  = (u16*)d_out;
  u16* Kb  = Qb + 4194304;

  const float SC2A = 0.0318793585f;  // log2(e)/sqrt(2048), folded into Q

  cvt_qkv<<<dim3(2048, 3), 256, 0, stream>>>(q, k, v, Xb);
  trans_w<<<dim3(16, 16, 4), dim3(64, 8), 0, stream>>>(Wq, Wk, Wv, Wo, Wt);
  gemm_proj<<<dim3(32, 8, 3), 256, 0, stream>>>(Xb, Wt, bq, bk, bv, Qb, Kb,
                                                VtG, SC2A);
  attn_k<<<dim3(32, 32), 256, 0, stream>>>(Qb, Kb, VtG, ctx);
  gemm_out<<<dim3(32, 8), 256, 0, stream>>>(ctx, Wt + 3 * 1048576, bo,
                                            (float*)d_out);
}